// Round 7
// baseline (12028.757 us; speedup 1.0000x reference)
//
#include <hip/hip_runtime.h>
#include <hip/hip_cooperative_groups.h>

namespace cg = cooperative_groups;

#define Bz   64
#define Tz   512
#define DIN  256
#define DOUT 1024
#define NWG  256
#define NTHR 512
#define PSTR 272   // K-partial per-ks stride; WAS 264 < max offset 267 -> LDS
                   // write collision (ks,rq=3,cq=3) vs (ks+1,rq=0,cq=0): the
                   // deterministic corruption behind R2-R6's 1.7617 failures.

// ---------------------------------------------------------------------------
// Pass 1: Z = x @ W_in + b_in -> written into d_out's ys region (row n = b*T+t,
// so Z[n,c] sits exactly where ys[b,t,c] goes). Unchanged (verified R1).
// ---------------------------------------------------------------------------
__global__ __launch_bounds__(256) void zgemm_kernel(
    const float* __restrict__ x, const float* __restrict__ Win,
    const float* __restrict__ bin, float* __restrict__ out)
{
    __shared__ float xT[32 * 132];
    __shared__ float ws[32 * 68];

    const int n0 = blockIdx.x * 128;
    const int c0 = blockIdx.y * 64;
    const int tid = threadIdx.x;
    const int tr = tid >> 4;
    const int tc = tid & 15;

    float acc[8][4];
#pragma unroll
    for (int i = 0; i < 8; ++i)
#pragma unroll
        for (int j = 0; j < 4; ++j) acc[i][j] = 0.f;

    for (int k0 = 0; k0 < DIN; k0 += 32) {
#pragma unroll
        for (int p = 0; p < 4; ++p) {
            int s = tid + p * 256;
            int r = s >> 3, kq = s & 7;
            float4 v = *(const float4*)(x + (size_t)(n0 + r) * DIN + k0 + kq * 4);
            xT[(kq * 4 + 0) * 132 + r] = v.x;
            xT[(kq * 4 + 1) * 132 + r] = v.y;
            xT[(kq * 4 + 2) * 132 + r] = v.z;
            xT[(kq * 4 + 3) * 132 + r] = v.w;
        }
#pragma unroll
        for (int p = 0; p < 2; ++p) {
            int s = tid + p * 256;
            int kk = s >> 4, cq = s & 15;
            *(float4*)(ws + kk * 68 + cq * 4) =
                *(const float4*)(Win + (size_t)(k0 + kk) * DOUT + c0 + cq * 4);
        }
        __syncthreads();
#pragma unroll
        for (int kk = 0; kk < 32; ++kk) {
            float4 a0 = *(const float4*)(xT + kk * 132 + tr * 4);
            float4 a1 = *(const float4*)(xT + kk * 132 + 64 + tr * 4);
            float4 b4 = *(const float4*)(ws + kk * 68 + tc * 4);
            float av[8] = {a0.x, a0.y, a0.z, a0.w, a1.x, a1.y, a1.z, a1.w};
            float bv[4] = {b4.x, b4.y, b4.z, b4.w};
#pragma unroll
            for (int i = 0; i < 8; ++i)
#pragma unroll
                for (int j = 0; j < 4; ++j)
                    acc[i][j] = fmaf(av[i], bv[j], acc[i][j]);
        }
        __syncthreads();
    }

    float4 bb = *(const float4*)(bin + c0 + tc * 4);
#pragma unroll
    for (int i = 0; i < 8; ++i) {
        int r = (i < 4) ? (tr * 4 + i) : (64 + tr * 4 + (i - 4));
        float4 o;
        o.x = acc[i][0] + bb.x;
        o.y = acc[i][1] + bb.y;
        o.z = acc[i][2] + bb.z;
        o.w = acc[i][3] + bb.w;
        *(float4*)(out + (size_t)(n0 + r) * DOUT + c0 + tc * 4) = o;
    }
}

// ---------------------------------------------------------------------------
// Pass 2a (primary): persistent cooperative kernel, ys-as-h.
// LDS = 131072 B (Whs 64KB + hls 64KB). h transport via system-scope atomics;
// barrier via grid.sync(). K-partial overlay stride fixed: PSTR=272.
// ---------------------------------------------------------------------------
__global__ __launch_bounds__(512, 1) void cwrnn_persistent(
    const float* __restrict__ Wh, const float* __restrict__ periods,
    const float* __restrict__ shifts, float* __restrict__ out)
{
    extern __shared__ float lds[];
    float* Whs = lds;            // [1024][16] = 16384 floats (64KB)
    float* hls = lds + 16384;    // [16][1024] = 16384 floats (64KB)
    float* P   = hls;            // K-partials overlay (max idx 8699 < 16384)

    cg::grid_group grid = cg::this_grid();

    const int bid = blockIdx.x;
    const int tid = threadIdx.x;
    const int r0 = (bid >> 6) * 16;    // row group
    const int c0 = (bid & 63) * 16;    // col group

    // ---- load Wh slice once ----
    {
        const int cq4 = tid & 3, kb = tid >> 2;   // kb 0..127
#pragma unroll
        for (int p = 0; p < 8; ++p) {
            int k = p * 128 + kb;
            *(float4*)(Whs + k * 16 + cq4 * 4) =
                *(const float4*)(Wh + (size_t)k * DOUT + c0 + cq4 * 4);
        }
    }
    __syncthreads();

    // ---- roles ----
    const bool owner = (tid < 256);
    const int orow = tid >> 4;
    const int occ  = tid & 15;
    const int oc   = c0 + occ;
    float pm = 0.f, sm = 0.f;
    if (owner) { pm = periods[oc >> 7]; sm = shifts[oc >> 7]; }

    const int cq = tid & 3;           // 4 cols
    const int rq = (tid >> 2) & 3;    // 4 rows
    const int ks = tid >> 4;          // 32-way K split: k = p*128 + ks*4 + j

    const int srow = tid >> 5;        // stage: 16 rows x 32 lanes
    const int skc  = tid & 31;

    for (int t = 0; t < Tz; ++t) {
        float zval = 0.f;
        const size_t zoff = (size_t)(r0 + orow) * ((size_t)Tz * DOUT)
                          + (size_t)t * DOUT + oc;
        if (owner) zval = out[zoff];   // sole reader/writer of this address

        float acc[4][4];
#pragma unroll
        for (int i = 0; i < 4; ++i)
#pragma unroll
            for (int j = 0; j < 4; ++j) acc[i][j] = 0.f;

        float hprev = 0.f;

        if (t > 0) {
            // ---- stage h = ys slice t-1 via coherent system atomics ----
            {
                const float* src = out
                    + (size_t)(r0 + srow) * ((size_t)Tz * DOUT)
                    + (size_t)(t - 1) * DOUT;
                float tmp[32];
#pragma unroll
                for (int i = 0; i < 32; ++i)
                    tmp[i] = __hip_atomic_load(src + i * 32 + skc,
                                               __ATOMIC_RELAXED,
                                               __HIP_MEMORY_SCOPE_SYSTEM);
                float* dst = hls + srow * 1024;
#pragma unroll
                for (int i = 0; i < 32; ++i)
                    dst[i * 32 + skc] = tmp[i];
            }
            __syncthreads();

            // ---- GEMM: acc[i][j] += h[rq*4+i][k] * W[k][cq*4+j] ----
            {
                const float* h0 = hls + (rq * 4 + 0) * 1024;
                const float* h1 = hls + (rq * 4 + 1) * 1024;
                const float* h2 = hls + (rq * 4 + 2) * 1024;
                const float* h3 = hls + (rq * 4 + 3) * 1024;
#pragma unroll
                for (int p = 0; p < 8; ++p) {
                    const int kb = p * 128 + ks * 4;
                    float4 w0 = *(const float4*)(Whs + (kb + 0) * 16 + cq * 4);
                    float4 w1 = *(const float4*)(Whs + (kb + 1) * 16 + cq * 4);
                    float4 w2 = *(const float4*)(Whs + (kb + 2) * 16 + cq * 4);
                    float4 w3 = *(const float4*)(Whs + (kb + 3) * 16 + cq * 4);
                    float4 ha = *(const float4*)(h0 + kb);
                    float4 hb = *(const float4*)(h1 + kb);
                    float4 hc = *(const float4*)(h2 + kb);
                    float4 hd = *(const float4*)(h3 + kb);
                    float hv[4][4] = {
                        {ha.x, ha.y, ha.z, ha.w}, {hb.x, hb.y, hb.z, hb.w},
                        {hc.x, hc.y, hc.z, hc.w}, {hd.x, hd.y, hd.z, hd.w}};
                    float4 wv[4] = {w0, w1, w2, w3};
#pragma unroll
                    for (int j = 0; j < 4; ++j)
#pragma unroll
                        for (int i = 0; i < 4; ++i) {
                            acc[i][0] = fmaf(hv[i][j], wv[j].x, acc[i][0]);
                            acc[i][1] = fmaf(hv[i][j], wv[j].y, acc[i][1]);
                            acc[i][2] = fmaf(hv[i][j], wv[j].z, acc[i][2]);
                            acc[i][3] = fmaf(hv[i][j], wv[j].w, acc[i][3]);
                        }
                }
            }
            __syncthreads();
            if (owner) hprev = hls[orow * 1024 + oc];
            __syncthreads();
        }

        // ---- K-partials into P (overlay on hls; hprev already in register) ----
        {
            float* pp = P + ks * PSTR + rq * 68 + cq * 4;
#pragma unroll
            for (int i = 0; i < 4; ++i) {
                pp[i * 16 + 0] = acc[i][0];
                pp[i * 16 + 1] = acc[i][1];
                pp[i * 16 + 2] = acc[i][2];
                pp[i * 16 + 3] = acc[i][3];
            }
        }
        __syncthreads();

        // ---- reduce + epilogue ----
        if (owner) {
            const float* pp = P + (orow >> 2) * 68 + (orow & 3) * 16 + occ;
            float sum = 0.f;
#pragma unroll
            for (int s = 0; s < 32; ++s) sum += pp[s * PSTR];
            float a = tanhf(zval + sum);
            float g = 0.5f * (sinf((float)t * pm + sm) + 1.0f);
            float y = (1.0f - g) * a + g * hprev;
            __hip_atomic_store(out + zoff, y, __ATOMIC_RELAXED,
                               __HIP_MEMORY_SCOPE_SYSTEM);   // ys[b,t,:] == h_{t+1}
            if (t == Tz - 1)
                out[(size_t)Bz * Tz * DOUT + (size_t)(r0 + orow) * DOUT + oc] = y;
        }

        if (t != Tz - 1) {
            __syncthreads();   // P-reads done; y stores drained before barrier
            grid.sync();
        }
    }
}

// ---------------------------------------------------------------------------
// Pass 2b (fallback): R1's VERIFIED per-step kernel (64KB static LDS, W_h from
// global, ping-pong h in d_ws). Used only if the cooperative path is refused.
// ---------------------------------------------------------------------------
__device__ __forceinline__ int hswz(int r, int idx) {
    return idx ^ r ^ ((idx >> 4) & 48);
}

__global__ __launch_bounds__(256) void step_kernel(
    int t, const float* __restrict__ h_in, float* __restrict__ h_out,
    const float* __restrict__ Wh, const float* __restrict__ periods,
    const float* __restrict__ shifts, float* __restrict__ out)
{
    __shared__ float hs[16 * 1024];

    const int cg_ = blockIdx.x & 63;
    const int rg = blockIdx.x >> 6;
    const int c0 = cg_ * 16;
    const int r0 = rg * 16;
    const int tid = threadIdx.x;

    {
        const int row = tid >> 4;
        const int sb  = tid & 15;
#pragma unroll
        for (int i = 0; i < 16; ++i) {
            int s = sb + i * 16;
            float4 v = *(const float4*)(h_in + (size_t)(r0 + row) * DOUT + s * 4);
            int base = row * 1024;
            hs[base + hswz(row, s * 4 + 0)] = v.x;
            hs[base + hswz(row, s * 4 + 1)] = v.y;
            hs[base + hswz(row, s * 4 + 2)] = v.z;
            hs[base + hswz(row, s * 4 + 3)] = v.w;
        }
    }
    __syncthreads();

    const int cq   = tid & 3;
    const int half = (tid >> 2) & 3;
    const int r    = tid >> 4;
    const int c    = c0 + cq * 4;
    const int k0h  = half * 256;
    const float* wp = Wh + c;
    const float* hp = hs + r * 1024;

    float a0 = 0.f, a1 = 0.f, a2 = 0.f, a3 = 0.f;
#pragma unroll 16
    for (int k = 0; k < 256; ++k) {
        int kk = k0h + k;
        float4 w4 = *(const float4*)(wp + (size_t)kk * DOUT);
        float hv = hp[hswz(r, kk)];
        a0 = fmaf(hv, w4.x, a0);
        a1 = fmaf(hv, w4.y, a1);
        a2 = fmaf(hv, w4.z, a2);
        a3 = fmaf(hv, w4.w, a3);
    }
    a0 += __shfl_xor(a0, 4); a0 += __shfl_xor(a0, 8);
    a1 += __shfl_xor(a1, 4); a1 += __shfl_xor(a1, 8);
    a2 += __shfl_xor(a2, 4); a2 += __shfl_xor(a2, 8);
    a3 += __shfl_xor(a3, 4); a3 += __shfl_xor(a3, 8);

    if (half == 0) {
        const int m = c >> 7;
        const float g  = 0.5f * (sinf((float)t * periods[m] + shifts[m]) + 1.0f);
        const float og = 1.0f - g;

        const size_t zidx = (size_t)(r0 + r) * ((size_t)Tz * DOUT) + (size_t)t * DOUT + c;
        float4 z4 = *(const float4*)(out + zidx);
        float h0 = hp[hswz(r, c + 0)];
        float h1 = hp[hswz(r, c + 1)];
        float h2 = hp[hswz(r, c + 2)];
        float h3 = hp[hswz(r, c + 3)];
        float4 y;
        y.x = og * tanhf(z4.x + a0) + g * h0;
        y.y = og * tanhf(z4.y + a1) + g * h1;
        y.z = og * tanhf(z4.z + a2) + g * h2;
        y.w = og * tanhf(z4.w + a3) + g * h3;
        *(float4*)(out + zidx) = y;
        *(float4*)(h_out + (size_t)(r0 + r) * DOUT + c) = y;
        if (t == Tz - 1)
            *(float4*)(out + (size_t)Bz * Tz * DOUT + (size_t)(r0 + r) * DOUT + c) = y;
    }
}

// ---------------------------------------------------------------------------
extern "C" void kernel_launch(void* const* d_in, const int* in_sizes, int n_in,
                              void* d_out, int out_size, void* d_ws, size_t ws_size,
                              hipStream_t stream)
{
    const float* x   = (const float*)d_in[0];
    const float* Win = (const float*)d_in[1];
    const float* bin = (const float*)d_in[2];
    const float* Wh  = (const float*)d_in[3];
    const float* per = (const float*)d_in[4];
    const float* shf = (const float*)d_in[5];
    float* out = (float*)d_out;

    zgemm_kernel<<<dim3(256, 16), 256, 0, stream>>>(x, Win, bin, out);

    const int ldsBytes = 131072;   // 128 KiB (Whs 64KB + hls 64KB)

    bool coop_ok = false;
    hipError_t err = hipFuncSetAttribute((const void*)cwrnn_persistent,
                        hipFuncAttributeMaxDynamicSharedMemorySize, ldsBytes);
    if (err == hipSuccess) {
        void* args[] = { (void*)&Wh, (void*)&per, (void*)&shf, (void*)&out };
        err = hipLaunchCooperativeKernel((const void*)cwrnn_persistent,
                                         dim3(NWG), dim3(NTHR), args,
                                         ldsBytes, stream);
        coop_ok = (err == hipSuccess);
    }

    if (!coop_ok) {
        // R1-verified fallback: per-step launches, ping-pong h in d_ws.
        float* ha = (float*)d_ws;
        float* hb = ha + (size_t)Bz * DOUT;
        hipMemsetAsync(ha, 0, (size_t)Bz * DOUT * sizeof(float), stream);
        for (int t = 0; t < Tz; ++t) {
            step_kernel<<<256, 256, 0, stream>>>(t, ha, hb, Wh, per, shf, out);
            float* tmp = ha; ha = hb; hb = tmp;
        }
    }
}